// Round 2
// baseline (167.424 us; speedup 1.0000x reference)
//
#include <hip/hip_runtime.h>

// TripletLoss on MI355X — round 9: occupancy + sort-cost fix.
//
//  - tl_sortk: single-block 1024-thread counting sort, LDS-only counters,
//    wave shfl-scan (2 barriers). Replaces the ~15us serial-scan version.
//  - tl_pass1s: BK=64 chunks, 2x[128][64] LDS = 32KB -> 4 blocks/CU
//    (was 64KB -> 2/CU, Occupancy 15.8%). Grid (16 j-splits x 64 strips)
//    = 1024 blocks = 4/CU exact. Same verified swizzle/mining structure.
//  - launch overhead floor ~50us is fixed; kernel count unchanged (4).

constexpr int N = 8192;
constexpr int D = 256;
constexpr float MARGIN = 0.3f;
constexpr float NEG_FALLBACK = 1e6f;
constexpr float TBIG = 1e30f;

typedef __attribute__((ext_vector_type(8))) __bf16 bf16x8;
typedef __attribute__((ext_vector_type(4))) float f32x4;

__device__ __forceinline__ unsigned enc_f(float f) {
  unsigned u = __float_as_uint(f);
  return (u >> 31) ? ~u : (u | 0x80000000u);
}
__device__ __forceinline__ float dec_f(unsigned e) {
  unsigned u = (e >> 31) ? (e ^ 0x80000000u) : ~e;
  return __uint_as_float(u);
}
__device__ __forceinline__ unsigned short f2bf_rtn(float x) {
  unsigned u = __float_as_uint(x);
  return (unsigned short)((u + 0x7fffu + ((u >> 16) & 1u)) >> 16);
}

// ---------------- sort: counting sort by label, 1 block x 1024 threads ------

__global__ __launch_bounds__(1024)
void tl_sortk(const int* __restrict__ labels, int* __restrict__ perm,
              int* __restrict__ labp, int* __restrict__ offg) {
  __shared__ int hist[512];
  __shared__ int wsum[8];
  __shared__ int wbase[8];
  const int tid = threadIdx.x;
  const int lane = tid & 63;
  const int w = tid >> 6;
  if (tid < 512) hist[tid] = 0;
  __syncthreads();
  int l8[8];
#pragma unroll
  for (int k = 0; k < 8; ++k) {
    l8[k] = labels[tid + k * 1024];  // coalesced
    atomicAdd(&hist[l8[k]], 1);      // LDS atomic
  }
  __syncthreads();
  int v = 0, sc = 0;
  if (tid < 512) {  // waves 0..7 scan the 512-entry histogram
    v = hist[tid];
    sc = v;
#pragma unroll
    for (int d = 1; d < 64; d <<= 1) {
      int t = __shfl_up(sc, d, 64);
      if (lane >= d) sc += t;
    }
    if (lane == 63) wsum[w] = sc;
  }
  __syncthreads();
  if (tid == 0) {
    int a = 0;
#pragma unroll
    for (int i = 0; i < 8; ++i) { wbase[i] = a; a += wsum[i]; }
  }
  __syncthreads();
  if (tid < 512) {
    const int excl = wbase[w] + sc - v;
    offg[tid] = excl;
    hist[tid] = excl;  // reuse as running scatter counters
  }
  if (tid == 0) offg[512] = N;
  __syncthreads();
#pragma unroll
  for (int k = 0; k < 8; ++k) {
    const int pos = atomicAdd(&hist[l8[k]], 1);  // LDS atomic
    perm[pos] = tid + k * 1024;
    labp[pos] = l8[k];
  }
}

// ---------------- pass 0: permuted bf16 convert + norms + init ----------------

__global__ void tl_pass0p(const float* __restrict__ feat, const int* __restrict__ perm,
                          float* __restrict__ norms, unsigned* __restrict__ ap,
                          unsigned* __restrict__ an, unsigned short* __restrict__ P,
                          float* __restrict__ out) {
  const int p = blockIdx.x * 4 + (threadIdx.x >> 6);
  const int lane = threadIdx.x & 63;
  const int src = perm[p];
  float4 f = reinterpret_cast<const float4*>(feat + (size_t)src * D)[lane];
  ushort4 h;
  h.x = f2bf_rtn(f.x); h.y = f2bf_rtn(f.y); h.z = f2bf_rtn(f.z); h.w = f2bf_rtn(f.w);
  reinterpret_cast<ushort4*>(P + (size_t)p * D)[lane] = h;
  float s = fmaf(f.x, f.x, fmaf(f.y, f.y, fmaf(f.z, f.z, f.w * f.w)));
#pragma unroll
  for (int off = 32; off > 0; off >>= 1) s += __shfl_down(s, off, 64);
  if (lane == 0) {
    norms[p] = s;
    ap[p] = enc_f(-TBIG);
    an[p] = enc_f(TBIG);
  }
  if (p == 0 && lane == 0) out[0] = 0.0f;
}

// ---------------- pass 1: persistent strip Gram + sorted mining ----------------

__global__ __launch_bounds__(256, 4)
void tl_pass1s(const unsigned short* __restrict__ P, const int* __restrict__ labp,
               const float* __restrict__ norms, const int* __restrict__ offg,
               unsigned* __restrict__ ap, unsigned* __restrict__ an) {
  __shared__ unsigned short lB[2][128][64];  // 32 KB double-buffered B chunk

  const int tid = threadIdx.x;
  const int wave = tid >> 6;
  const int lane = tid & 63;
  const int c = lane & 15;
  const int q = lane >> 4;
  const int i0 = blockIdx.y * 128;   // strip base row (permuted space)
  const int j0 = blockIdx.x * 512;   // this block's column range
  const int wrow = i0 + wave * 32;   // wave's 32 output rows

  // careful j-range for this strip: columns whose label matches any strip row
  const int lo = offg[labp[i0]];
  const int hi = offg[labp[i0 + 127] + 1];

  // A fragments in registers for the whole block: af[a][kg] = P[row][kg*32+q*8]
  bf16x8 af[2][8];
#pragma unroll
  for (int a = 0; a < 2; ++a)
#pragma unroll
    for (int t2 = 0; t2 < 8; ++t2)
      af[a][t2] = *(const bf16x8*)(P + (size_t)(wrow + a * 16 + c) * D + t2 * 32 + q * 8);

  f32x4 acc[2][8];
#pragma unroll
  for (int a = 0; a < 2; ++a)
#pragma unroll
    for (int b = 0; b < 8; ++b) acc[a][b] = (f32x4){0.f, 0.f, 0.f, 0.f};

  float vp[2][4], vn[2][4];
#pragma unroll
  for (int a = 0; a < 2; ++a)
#pragma unroll
    for (int r = 0; r < 4; ++r) { vp[a][r] = -TBIG; vn[a][r] = TBIG; }

  const int rsub = lane >> 3;  // 0..7: row within 8-row DMA group
  const int g7 = lane & 7;     // 8-short column group within 64-short row

  // Stage one [128 cols][64 K] chunk. LDS dest linear (wave-uniform base +
  // lane*16B); SOURCE pre-swizzled so LDS[r][g] = P[r][kc + (g ^ (r&7))*8].
#define STAGE(S1)                                                                       \
  do {                                                                                  \
    const int jt_ = (S1) >> 2;                                                          \
    const int kc_ = ((S1) & 3) * 64;                                                    \
    const int jb_ = j0 + jt_ * 128;                                                     \
    const int buf_ = (S1) & 1;                                                          \
    _Pragma("unroll") for (int t = 0; t < 4; ++t) {                                     \
      const int rA_ = wave * 32 + t * 8;                                                \
      const int sg_ = g7 ^ rsub;                                                        \
      const unsigned short* gp_ = P + (size_t)(jb_ + rA_ + rsub) * D + kc_ + sg_ * 8;   \
      __builtin_amdgcn_global_load_lds(                                                 \
          (const __attribute__((address_space(1))) void*)gp_,                           \
          (__attribute__((address_space(3))) void*)&lB[buf_][rA_][0], 16, 0, 0);        \
    }                                                                                   \
  } while (0)

  STAGE(0);
  __syncthreads();

#pragma unroll
  for (int jt = 0; jt < 4; ++jt) {
#pragma unroll
    for (int kk = 0; kk < 4; ++kk) {
      const int s = jt * 4 + kk;
      if (s < 15) STAGE(s + 1);  // prefetch next chunk; drained at the barrier

      // compute chunk s from buffer s&1: K-groups kk*2, kk*2+1
#pragma unroll
      for (int ks = 0; ks < 2; ++ks) {
        const int gsel = ((ks * 4 + q) ^ (c & 7)) * 8;
        bf16x8 bfr[8];
#pragma unroll
        for (int b = 0; b < 8; ++b)
          bfr[b] = *(const bf16x8*)&lB[s & 1][b * 16 + c][gsel];
#pragma unroll
        for (int a = 0; a < 2; ++a)
#pragma unroll
          for (int b = 0; b < 8; ++b)
            acc[a][b] = __builtin_amdgcn_mfma_f32_16x16x32_bf16(
                af[a][kk * 2 + ks], bfr[b], acc[a][b], 0, 0, 0);
      }

      if (kk == 3) {  // j-tile complete -> mine it
        const int jb0 = j0 + jt * 128;
        const bool careful = (jb0 < hi) && (jb0 + 128 > lo);  // block-uniform
        if (!careful) {
          // pure negatives: 2 VALU ops per element
#pragma unroll
          for (int b = 0; b < 8; ++b) {
            const float njb = norms[jb0 + b * 16 + c];
#pragma unroll
            for (int a = 0; a < 2; ++a)
#pragma unroll
              for (int r = 0; r < 4; ++r)
                vn[a][r] = fminf(vn[a][r], fmaf(-2.f, acc[a][b][r], njb));
          }
        } else {
          int lj[8], cj[8];
          float nj[8];
#pragma unroll
          for (int b = 0; b < 8; ++b) {
            cj[b] = jb0 + b * 16 + c;
            nj[b] = norms[cj[b]];
            lj[b] = labp[cj[b]];
          }
#pragma unroll
          for (int a = 0; a < 2; ++a)
#pragma unroll
            for (int r = 0; r < 4; ++r) {
              const int rg = wrow + a * 16 + q * 4 + r;  // C/D row = q*4 + reg
              const int li = labp[rg];
              float vpl = vp[a][r], vnl = vn[a][r];
#pragma unroll
              for (int b = 0; b < 8; ++b) {
                const float t = fmaf(-2.f, acc[a][b][r], nj[b]);
                const bool sm = (lj[b] == li);
                const bool dg = (cj[b] == rg);
                vpl = fmaxf(vpl, (sm && !dg) ? t : -TBIG);
                vnl = fminf(vnl, sm ? TBIG : t);
              }
              vp[a][r] = vpl;
              vn[a][r] = vnl;
            }
        }
#pragma unroll
        for (int a = 0; a < 2; ++a)
#pragma unroll
          for (int b = 0; b < 8; ++b) acc[a][b] = (f32x4){0.f, 0.f, 0.f, 0.f};
      }
      __syncthreads();
    }
  }
#undef STAGE

  // epilogue once per block: reduce over the 16 c-lanes, then 1 atomic pair/row
#pragma unroll
  for (int a = 0; a < 2; ++a)
#pragma unroll
    for (int r = 0; r < 4; ++r) {
      float p = vp[a][r], n = vn[a][r];
#pragma unroll
      for (int m = 1; m < 16; m <<= 1) {
        p = fmaxf(p, __shfl_xor(p, m, 64));
        n = fminf(n, __shfl_xor(n, m, 64));
      }
      if (c == 0) {
        const int rg = wrow + a * 16 + q * 4 + r;
        atomicMax(&ap[rg], enc_f(p));
        atomicMin(&an[rg], enc_f(n));
      }
    }
}

// ---------------- pass 2: per-row loss -> mean (permuted space; mean invariant) --

__global__ void tl_pass2f(const unsigned* __restrict__ ap, const unsigned* __restrict__ an,
                          const float* __restrict__ norms, float* __restrict__ out) {
  int r = blockIdx.x * 256 + threadIdx.x;
  float ni = norms[r];
  float tpv = dec_f(ap[r]);
  float tnv = dec_f(an[r]);
  float dap = (tpv < -1e29f) ? 0.f : sqrtf(fmaxf(ni + tpv, 0.f));
  float dan = (tnv > 1e29f) ? NEG_FALLBACK : sqrtf(fmaxf(ni + tnv, 0.f));
  float v = fmaxf(0.f, MARGIN + dap - dan) * (1.0f / (float)N);
#pragma unroll
  for (int off = 32; off > 0; off >>= 1) v += __shfl_down(v, off, 64);
  __shared__ float red[4];
  int lane = threadIdx.x & 63, w = threadIdx.x >> 6;
  if (lane == 0) red[w] = v;
  __syncthreads();
  if (threadIdx.x == 0) atomicAdd(out, red[0] + red[1] + red[2] + red[3]);
}

// ---------------- fallback fp32 path (small ws) — round-1 known-good ----------------

constexpr int FB_BK = 32;
constexpr int FB_JSPLIT = 8;
constexpr int FB_JRANGE = N / FB_JSPLIT;
constexpr int FB_LDS = 132;

__global__ void tl_pass0_fb(const float* __restrict__ feat, float* __restrict__ norms,
                            float* __restrict__ ap, float* __restrict__ an,
                            float* __restrict__ out) {
  int row = blockIdx.x * 4 + (threadIdx.x >> 6);
  int lane = threadIdx.x & 63;
  float4 f = reinterpret_cast<const float4*>(feat + (size_t)row * D)[lane];
  float s = f.x * f.x + f.y * f.y + f.z * f.z + f.w * f.w;
#pragma unroll
  for (int off = 32; off > 0; off >>= 1) s += __shfl_down(s, off, 64);
  if (lane == 0) { norms[row] = s; ap[row] = 0.0f; an[row] = NEG_FALLBACK; }
  if (row == 0 && lane == 0) out[0] = 0.0f;
}

__global__ __launch_bounds__(256, 2)
void tl_pass1_fb(const float* __restrict__ feat, const int* __restrict__ labels,
                 const float* __restrict__ norms,
                 unsigned int* __restrict__ ap, unsigned int* __restrict__ an) {
  __shared__ float As[FB_BK][FB_LDS];
  __shared__ float Bs[FB_BK][FB_LDS];
  const int tid = threadIdx.x;
  const int tx = tid & 15, ty = tid >> 4;
  const int ib0 = blockIdx.y * 128;
  const int jbase = blockIdx.x * FB_JRANGE;
  float ni[8]; int li[8]; int ri[8];
#pragma unroll
  for (int a = 0; a < 8; ++a) {
    int r = ty * 4 + (a & 3) + ((a >> 2) << 6);
    ri[a] = ib0 + r; ni[a] = norms[ri[a]]; li[a] = labels[ri[a]];
  }
  float apv[8], anv[8];
#pragma unroll
  for (int a = 0; a < 8; ++a) { apv[a] = 0.0f; anv[a] = NEG_FALLBACK; }
  for (int jt = 0; jt < FB_JRANGE; jt += 128) {
    const int jb = jbase + jt;
    float acc[8][8];
#pragma unroll
    for (int a = 0; a < 8; ++a)
#pragma unroll
      for (int b = 0; b < 8; ++b) acc[a][b] = 0.0f;
    for (int kc = 0; kc < D; kc += FB_BK) {
#pragma unroll
      for (int u = 0; u < 4; ++u) {
        int lin = tid + u * 256;
        int row = lin >> 3, c4 = lin & 7;
        float4 va = *reinterpret_cast<const float4*>(feat + (size_t)(ib0 + row) * D + kc + c4 * 4);
        As[c4 * 4 + 0][row] = va.x; As[c4 * 4 + 1][row] = va.y;
        As[c4 * 4 + 2][row] = va.z; As[c4 * 4 + 3][row] = va.w;
        float4 vb = *reinterpret_cast<const float4*>(feat + (size_t)(jb + row) * D + kc + c4 * 4);
        Bs[c4 * 4 + 0][row] = vb.x; Bs[c4 * 4 + 1][row] = vb.y;
        Bs[c4 * 4 + 2][row] = vb.z; Bs[c4 * 4 + 3][row] = vb.w;
      }
      __syncthreads();
#pragma unroll 8
      for (int k = 0; k < FB_BK; ++k) {
        float4 a0 = *reinterpret_cast<const float4*>(&As[k][ty * 4]);
        float4 a1 = *reinterpret_cast<const float4*>(&As[k][64 + ty * 4]);
        float4 b0 = *reinterpret_cast<const float4*>(&Bs[k][tx * 4]);
        float4 b1 = *reinterpret_cast<const float4*>(&Bs[k][64 + tx * 4]);
        float av[8] = {a0.x, a0.y, a0.z, a0.w, a1.x, a1.y, a1.z, a1.w};
        float bv[8] = {b0.x, b0.y, b0.z, b0.w, b1.x, b1.y, b1.z, b1.w};
#pragma unroll
        for (int a = 0; a < 8; ++a)
#pragma unroll
          for (int b = 0; b < 8; ++b) acc[a][b] = fmaf(av[a], bv[b], acc[a][b]);
      }
      __syncthreads();
    }
#pragma unroll
    for (int b = 0; b < 8; ++b) {
      int cjx = jb + tx * 4 + (b & 3) + ((b >> 2) << 6);
      float njx = norms[cjx]; int ljx = labels[cjx];
#pragma unroll
      for (int a = 0; a < 8; ++a) {
        float sq = fmaxf(ni[a] + njx - 2.0f * acc[a][b], 0.0f);
        float dist = sqrtf(sq);
        if (li[a] == ljx) { if (ri[a] != cjx) apv[a] = fmaxf(apv[a], dist); }
        else anv[a] = fminf(anv[a], dist);
      }
    }
  }
  __syncthreads();
  float* red = &As[0][0];
#pragma unroll
  for (int a = 0; a < 8; ++a) {
    int r = ty * 4 + (a & 3) + ((a >> 2) << 6);
    red[r * 16 + tx] = apv[a];
  }
  __syncthreads();
  if (tid < 128) {
    float m = red[tid * 16];
#pragma unroll
    for (int t = 1; t < 16; ++t) m = fmaxf(m, red[tid * 16 + t]);
    atomicMax(&ap[ib0 + tid], __float_as_uint(m));
  }
  __syncthreads();
#pragma unroll
  for (int a = 0; a < 8; ++a) {
    int r = ty * 4 + (a & 3) + ((a >> 2) << 6);
    red[r * 16 + tx] = anv[a];
  }
  __syncthreads();
  if (tid < 128) {
    float m = red[tid * 16];
#pragma unroll
    for (int t = 1; t < 16; ++t) m = fminf(m, red[tid * 16 + t]);
    atomicMin(&an[ib0 + tid], __float_as_uint(m));
  }
}

__global__ void tl_pass2_fb(const float* __restrict__ ap, const float* __restrict__ an,
                            float* __restrict__ out) {
  int r = blockIdx.x * 256 + threadIdx.x;
  float v = fmaxf(0.0f, MARGIN + ap[r] - an[r]) * (1.0f / (float)N);
#pragma unroll
  for (int off = 32; off > 0; off >>= 1) v += __shfl_down(v, off, 64);
  __shared__ float red[4];
  int lane = threadIdx.x & 63, w = threadIdx.x >> 6;
  if (lane == 0) red[w] = v;
  __syncthreads();
  if (threadIdx.x == 0) atomicAdd(out, red[0] + red[1] + red[2] + red[3]);
}

// ---------------- launch ----------------

extern "C" void kernel_launch(void* const* d_in, const int* in_sizes, int n_in,
                              void* d_out, int out_size, void* d_ws, size_t ws_size,
                              hipStream_t stream) {
  const float* feat = (const float*)d_in[0];
  const int* labels = (const int*)d_in[1];
  float* out = (float*)d_out;

  // ws: norms[N] f32 | ap[N] u32 | an[N] u32 | perm[N] i32 | labp[N] i32 |
  //     off[520] i32 | P[N*D] bf16   (P offset 16B-aligned)
  float* norms = (float*)d_ws;
  unsigned* ap = (unsigned*)(norms + N);
  unsigned* an = ap + N;
  int* perm = (int*)(an + N);
  int* labp = perm + N;
  int* offg = labp + N;
  unsigned short* P = (unsigned short*)(offg + 520);
  const size_t NEED = (size_t)5 * N * 4 + 520 * 4 + (size_t)N * D * 2;

  if (ws_size >= NEED) {
    tl_sortk<<<1, 1024, 0, stream>>>(labels, perm, labp, offg);
    tl_pass0p<<<N / 4, 256, 0, stream>>>(feat, perm, norms, ap, an, P, out);
    dim3 grid1(16, N / 128);  // 16 j-splits x 64 strips = 1024 blocks (4/CU)
    tl_pass1s<<<grid1, 256, 0, stream>>>(P, labp, norms, offg, ap, an);
    tl_pass2f<<<N / 256, 256, 0, stream>>>(ap, an, norms, out);
  } else {
    float* apf = (float*)ap;
    float* anf = (float*)an;
    tl_pass0_fb<<<N / 4, 256, 0, stream>>>(feat, norms, apf, anf, out);
    dim3 grid1(FB_JSPLIT, N / 128);
    tl_pass1_fb<<<grid1, 256, 0, stream>>>(feat, labels, norms, (unsigned*)apf, (unsigned*)anf);
    tl_pass2_fb<<<N / 256, 256, 0, stream>>>(apf, anf, out);
  }
}

// Round 3
// 148.432 us; speedup vs baseline: 1.1279x; 1.1279x over previous
//
#include <hip/hip_runtime.h>

// TripletLoss on MI355X — round 10: fix round-9's register spill.
//
//  - Round-9 postmortem: __launch_bounds__(256,4) capped VGPR at 128 while
//    af[64]+acc[64] alone need 128 -> massive scratch spill (WRITE_SIZE
//    183MB, VGPR_Count 64, 98us). Fix: (256,3) cap ~170 + shrink live
//    ranges (runtime jt loop, only kk 4-step unrolled; buffer parity kk&1
//    is compile-time since every j-tile is an even 4 chunks).
//  - BK=64 chunks, 2x[128][64] LDS = 32KB; grid 16x64=1024 blocks; 3/CU
//    by VGPR (LDS would allow 5).
//  - sortk/pass0p/pass2f unchanged (sortk's 1024-thread version is fast).

constexpr int N = 8192;
constexpr int D = 256;
constexpr float MARGIN = 0.3f;
constexpr float NEG_FALLBACK = 1e6f;
constexpr float TBIG = 1e30f;

typedef __attribute__((ext_vector_type(8))) __bf16 bf16x8;
typedef __attribute__((ext_vector_type(4))) float f32x4;

__device__ __forceinline__ unsigned enc_f(float f) {
  unsigned u = __float_as_uint(f);
  return (u >> 31) ? ~u : (u | 0x80000000u);
}
__device__ __forceinline__ float dec_f(unsigned e) {
  unsigned u = (e >> 31) ? (e ^ 0x80000000u) : ~e;
  return __uint_as_float(u);
}
__device__ __forceinline__ unsigned short f2bf_rtn(float x) {
  unsigned u = __float_as_uint(x);
  return (unsigned short)((u + 0x7fffu + ((u >> 16) & 1u)) >> 16);
}

// ---------------- sort: counting sort by label, 1 block x 1024 threads ------

__global__ __launch_bounds__(1024)
void tl_sortk(const int* __restrict__ labels, int* __restrict__ perm,
              int* __restrict__ labp, int* __restrict__ offg) {
  __shared__ int hist[512];
  __shared__ int wsum[8];
  __shared__ int wbase[8];
  const int tid = threadIdx.x;
  const int lane = tid & 63;
  const int w = tid >> 6;
  if (tid < 512) hist[tid] = 0;
  __syncthreads();
  int l8[8];
#pragma unroll
  for (int k = 0; k < 8; ++k) {
    l8[k] = labels[tid + k * 1024];  // coalesced
    atomicAdd(&hist[l8[k]], 1);      // LDS atomic
  }
  __syncthreads();
  int v = 0, sc = 0;
  if (tid < 512) {  // waves 0..7 scan the 512-entry histogram
    v = hist[tid];
    sc = v;
#pragma unroll
    for (int d = 1; d < 64; d <<= 1) {
      int t = __shfl_up(sc, d, 64);
      if (lane >= d) sc += t;
    }
    if (lane == 63) wsum[w] = sc;
  }
  __syncthreads();
  if (tid == 0) {
    int a = 0;
#pragma unroll
    for (int i = 0; i < 8; ++i) { wbase[i] = a; a += wsum[i]; }
  }
  __syncthreads();
  if (tid < 512) {
    const int excl = wbase[w] + sc - v;
    offg[tid] = excl;
    hist[tid] = excl;  // reuse as running scatter counters
  }
  if (tid == 0) offg[512] = N;
  __syncthreads();
#pragma unroll
  for (int k = 0; k < 8; ++k) {
    const int pos = atomicAdd(&hist[l8[k]], 1);  // LDS atomic
    perm[pos] = tid + k * 1024;
    labp[pos] = l8[k];
  }
}

// ---------------- pass 0: permuted bf16 convert + norms + init ----------------

__global__ void tl_pass0p(const float* __restrict__ feat, const int* __restrict__ perm,
                          float* __restrict__ norms, unsigned* __restrict__ ap,
                          unsigned* __restrict__ an, unsigned short* __restrict__ P,
                          float* __restrict__ out) {
  const int p = blockIdx.x * 4 + (threadIdx.x >> 6);
  const int lane = threadIdx.x & 63;
  const int src = perm[p];
  float4 f = reinterpret_cast<const float4*>(feat + (size_t)src * D)[lane];
  ushort4 h;
  h.x = f2bf_rtn(f.x); h.y = f2bf_rtn(f.y); h.z = f2bf_rtn(f.z); h.w = f2bf_rtn(f.w);
  reinterpret_cast<ushort4*>(P + (size_t)p * D)[lane] = h;
  float s = fmaf(f.x, f.x, fmaf(f.y, f.y, fmaf(f.z, f.z, f.w * f.w)));
#pragma unroll
  for (int off = 32; off > 0; off >>= 1) s += __shfl_down(s, off, 64);
  if (lane == 0) {
    norms[p] = s;
    ap[p] = enc_f(-TBIG);
    an[p] = enc_f(TBIG);
  }
  if (p == 0 && lane == 0) out[0] = 0.0f;
}

// ---------------- pass 1: persistent strip Gram + sorted mining ----------------

__global__ __launch_bounds__(256, 3)
void tl_pass1s(const unsigned short* __restrict__ P, const int* __restrict__ labp,
               const float* __restrict__ norms, const int* __restrict__ offg,
               unsigned* __restrict__ ap, unsigned* __restrict__ an) {
  __shared__ unsigned short lB[2][128][64];  // 32 KB double-buffered B chunk

  const int tid = threadIdx.x;
  const int wave = tid >> 6;
  const int lane = tid & 63;
  const int c = lane & 15;
  const int q = lane >> 4;
  const int i0 = blockIdx.y * 128;   // strip base row (permuted space)
  const int j0 = blockIdx.x * 512;   // this block's column range
  const int wrow = i0 + wave * 32;   // wave's 32 output rows

  // careful j-range for this strip: columns whose label matches any strip row
  const int lo = offg[labp[i0]];
  const int hi = offg[labp[i0 + 127] + 1];

  // A fragments in registers for the whole block: af[a][kg] = P[row][kg*32+q*8]
  bf16x8 af[2][8];
#pragma unroll
  for (int a = 0; a < 2; ++a)
#pragma unroll
    for (int t2 = 0; t2 < 8; ++t2)
      af[a][t2] = *(const bf16x8*)(P + (size_t)(wrow + a * 16 + c) * D + t2 * 32 + q * 8);

  f32x4 acc[2][8];
#pragma unroll
  for (int a = 0; a < 2; ++a)
#pragma unroll
    for (int b = 0; b < 8; ++b) acc[a][b] = (f32x4){0.f, 0.f, 0.f, 0.f};

  float vp[2][4], vn[2][4];
#pragma unroll
  for (int a = 0; a < 2; ++a)
#pragma unroll
    for (int r = 0; r < 4; ++r) { vp[a][r] = -TBIG; vn[a][r] = TBIG; }

  const int rsub = lane >> 3;  // 0..7: row within 8-row DMA group
  const int g7 = lane & 7;     // 8-short column group within 64-short row

  // Stage one [128 cols][64 K] chunk. LDS dest linear (wave-uniform base +
  // lane*16B); SOURCE pre-swizzled so LDS[r][g] = P[r][kc + (g ^ (r&7))*8].
  // BUF and KC are compile-time literals; JT may be runtime.
#define STAGE(BUF, JT, KC)                                                              \
  do {                                                                                  \
    const int jb_ = j0 + (JT) * 128;                                                    \
    _Pragma("unroll") for (int t = 0; t < 4; ++t) {                                     \
      const int rA_ = wave * 32 + t * 8;                                                \
      const int sg_ = g7 ^ rsub;                                                        \
      const unsigned short* gp_ = P + (size_t)(jb_ + rA_ + rsub) * D + (KC) + sg_ * 8;  \
      __builtin_amdgcn_global_load_lds(                                                 \
          (const __attribute__((address_space(1))) void*)gp_,                           \
          (__attribute__((address_space(3))) void*)&lB[BUF][rA_][0], 16, 0, 0);         \
    }                                                                                   \
  } while (0)

  STAGE(0, 0, 0);
  __syncthreads();

#pragma unroll 1
  for (int jt = 0; jt < 4; ++jt) {
#pragma unroll
    for (int kk = 0; kk < 4; ++kk) {
      // prefetch next chunk; buffer parity is kk&1 (4 chunks per j-tile)
      if (kk < 3) {
        STAGE((kk + 1) & 1, jt, (kk + 1) * 64);
      } else if (jt < 3) {
        STAGE(0, jt + 1, 0);
      }

      // compute chunk kk from buffer kk&1: K-groups kk*2, kk*2+1
#pragma unroll
      for (int ks = 0; ks < 2; ++ks) {
        const int gsel = ((ks * 4 + q) ^ (c & 7)) * 8;
        bf16x8 bfr[8];
#pragma unroll
        for (int b = 0; b < 8; ++b)
          bfr[b] = *(const bf16x8*)&lB[kk & 1][b * 16 + c][gsel];
#pragma unroll
        for (int a = 0; a < 2; ++a)
#pragma unroll
          for (int b = 0; b < 8; ++b)
            acc[a][b] = __builtin_amdgcn_mfma_f32_16x16x32_bf16(
                af[a][kk * 2 + ks], bfr[b], acc[a][b], 0, 0, 0);
      }

      if (kk == 3) {  // j-tile complete -> mine it
        const int jb0 = j0 + jt * 128;
        const bool careful = (jb0 < hi) && (jb0 + 128 > lo);  // block-uniform
        if (!careful) {
          // pure negatives: 2 VALU ops per element
#pragma unroll
          for (int b = 0; b < 8; ++b) {
            const float njb = norms[jb0 + b * 16 + c];
#pragma unroll
            for (int a = 0; a < 2; ++a)
#pragma unroll
              for (int r = 0; r < 4; ++r)
                vn[a][r] = fminf(vn[a][r], fmaf(-2.f, acc[a][b][r], njb));
          }
        } else {
          int lj[8], cj[8];
          float nj[8];
#pragma unroll
          for (int b = 0; b < 8; ++b) {
            cj[b] = jb0 + b * 16 + c;
            nj[b] = norms[cj[b]];
            lj[b] = labp[cj[b]];
          }
#pragma unroll
          for (int a = 0; a < 2; ++a)
#pragma unroll
            for (int r = 0; r < 4; ++r) {
              const int rg = wrow + a * 16 + q * 4 + r;  // C/D row = q*4 + reg
              const int li = labp[rg];
              float vpl = vp[a][r], vnl = vn[a][r];
#pragma unroll
              for (int b = 0; b < 8; ++b) {
                const float t = fmaf(-2.f, acc[a][b][r], nj[b]);
                const bool sm = (lj[b] == li);
                const bool dg = (cj[b] == rg);
                vpl = fmaxf(vpl, (sm && !dg) ? t : -TBIG);
                vnl = fminf(vnl, sm ? TBIG : t);
              }
              vp[a][r] = vpl;
              vn[a][r] = vnl;
            }
        }
#pragma unroll
        for (int a = 0; a < 2; ++a)
#pragma unroll
          for (int b = 0; b < 8; ++b) acc[a][b] = (f32x4){0.f, 0.f, 0.f, 0.f};
      }
      __syncthreads();
    }
  }
#undef STAGE

  // epilogue once per block: reduce over the 16 c-lanes, then 1 atomic pair/row
#pragma unroll
  for (int a = 0; a < 2; ++a)
#pragma unroll
    for (int r = 0; r < 4; ++r) {
      float p = vp[a][r], n = vn[a][r];
#pragma unroll
      for (int m = 1; m < 16; m <<= 1) {
        p = fmaxf(p, __shfl_xor(p, m, 64));
        n = fminf(n, __shfl_xor(n, m, 64));
      }
      if (c == 0) {
        const int rg = wrow + a * 16 + q * 4 + r;
        atomicMax(&ap[rg], enc_f(p));
        atomicMin(&an[rg], enc_f(n));
      }
    }
}

// ---------------- pass 2: per-row loss -> mean (permuted space; mean invariant) --

__global__ void tl_pass2f(const unsigned* __restrict__ ap, const unsigned* __restrict__ an,
                          const float* __restrict__ norms, float* __restrict__ out) {
  int r = blockIdx.x * 256 + threadIdx.x;
  float ni = norms[r];
  float tpv = dec_f(ap[r]);
  float tnv = dec_f(an[r]);
  float dap = (tpv < -1e29f) ? 0.f : sqrtf(fmaxf(ni + tpv, 0.f));
  float dan = (tnv > 1e29f) ? NEG_FALLBACK : sqrtf(fmaxf(ni + tnv, 0.f));
  float v = fmaxf(0.f, MARGIN + dap - dan) * (1.0f / (float)N);
#pragma unroll
  for (int off = 32; off > 0; off >>= 1) v += __shfl_down(v, off, 64);
  __shared__ float red[4];
  int lane = threadIdx.x & 63, w = threadIdx.x >> 6;
  if (lane == 0) red[w] = v;
  __syncthreads();
  if (threadIdx.x == 0) atomicAdd(out, red[0] + red[1] + red[2] + red[3]);
}

// ---------------- fallback fp32 path (small ws) — round-1 known-good ----------------

constexpr int FB_BK = 32;
constexpr int FB_JSPLIT = 8;
constexpr int FB_JRANGE = N / FB_JSPLIT;
constexpr int FB_LDS = 132;

__global__ void tl_pass0_fb(const float* __restrict__ feat, float* __restrict__ norms,
                            float* __restrict__ ap, float* __restrict__ an,
                            float* __restrict__ out) {
  int row = blockIdx.x * 4 + (threadIdx.x >> 6);
  int lane = threadIdx.x & 63;
  float4 f = reinterpret_cast<const float4*>(feat + (size_t)row * D)[lane];
  float s = f.x * f.x + f.y * f.y + f.z * f.z + f.w * f.w;
#pragma unroll
  for (int off = 32; off > 0; off >>= 1) s += __shfl_down(s, off, 64);
  if (lane == 0) { norms[row] = s; ap[row] = 0.0f; an[row] = NEG_FALLBACK; }
  if (row == 0 && lane == 0) out[0] = 0.0f;
}

__global__ __launch_bounds__(256, 2)
void tl_pass1_fb(const float* __restrict__ feat, const int* __restrict__ labels,
                 const float* __restrict__ norms,
                 unsigned int* __restrict__ ap, unsigned int* __restrict__ an) {
  __shared__ float As[FB_BK][FB_LDS];
  __shared__ float Bs[FB_BK][FB_LDS];
  const int tid = threadIdx.x;
  const int tx = tid & 15, ty = tid >> 4;
  const int ib0 = blockIdx.y * 128;
  const int jbase = blockIdx.x * FB_JRANGE;
  float ni[8]; int li[8]; int ri[8];
#pragma unroll
  for (int a = 0; a < 8; ++a) {
    int r = ty * 4 + (a & 3) + ((a >> 2) << 6);
    ri[a] = ib0 + r; ni[a] = norms[ri[a]]; li[a] = labels[ri[a]];
  }
  float apv[8], anv[8];
#pragma unroll
  for (int a = 0; a < 8; ++a) { apv[a] = 0.0f; anv[a] = NEG_FALLBACK; }
  for (int jt = 0; jt < FB_JRANGE; jt += 128) {
    const int jb = jbase + jt;
    float acc[8][8];
#pragma unroll
    for (int a = 0; a < 8; ++a)
#pragma unroll
      for (int b = 0; b < 8; ++b) acc[a][b] = 0.0f;
    for (int kc = 0; kc < D; kc += FB_BK) {
#pragma unroll
      for (int u = 0; u < 4; ++u) {
        int lin = tid + u * 256;
        int row = lin >> 3, c4 = lin & 7;
        float4 va = *reinterpret_cast<const float4*>(feat + (size_t)(ib0 + row) * D + kc + c4 * 4);
        As[c4 * 4 + 0][row] = va.x; As[c4 * 4 + 1][row] = va.y;
        As[c4 * 4 + 2][row] = va.z; As[c4 * 4 + 3][row] = va.w;
        float4 vb = *reinterpret_cast<const float4*>(feat + (size_t)(jb + row) * D + kc + c4 * 4);
        Bs[c4 * 4 + 0][row] = vb.x; Bs[c4 * 4 + 1][row] = vb.y;
        Bs[c4 * 4 + 2][row] = vb.z; Bs[c4 * 4 + 3][row] = vb.w;
      }
      __syncthreads();
#pragma unroll 8
      for (int k = 0; k < FB_BK; ++k) {
        float4 a0 = *reinterpret_cast<const float4*>(&As[k][ty * 4]);
        float4 a1 = *reinterpret_cast<const float4*>(&As[k][64 + ty * 4]);
        float4 b0 = *reinterpret_cast<const float4*>(&Bs[k][tx * 4]);
        float4 b1 = *reinterpret_cast<const float4*>(&Bs[k][64 + tx * 4]);
        float av[8] = {a0.x, a0.y, a0.z, a0.w, a1.x, a1.y, a1.z, a1.w};
        float bv[8] = {b0.x, b0.y, b0.z, b0.w, b1.x, b1.y, b1.z, b1.w};
#pragma unroll
        for (int a = 0; a < 8; ++a)
#pragma unroll
          for (int b = 0; b < 8; ++b) acc[a][b] = fmaf(av[a], bv[b], acc[a][b]);
      }
      __syncthreads();
    }
#pragma unroll
    for (int b = 0; b < 8; ++b) {
      int cjx = jb + tx * 4 + (b & 3) + ((b >> 2) << 6);
      float njx = norms[cjx]; int ljx = labels[cjx];
#pragma unroll
      for (int a = 0; a < 8; ++a) {
        float sq = fmaxf(ni[a] + njx - 2.0f * acc[a][b], 0.0f);
        float dist = sqrtf(sq);
        if (li[a] == ljx) { if (ri[a] != cjx) apv[a] = fmaxf(apv[a], dist); }
        else anv[a] = fminf(anv[a], dist);
      }
    }
  }
  __syncthreads();
  float* red = &As[0][0];
#pragma unroll
  for (int a = 0; a < 8; ++a) {
    int r = ty * 4 + (a & 3) + ((a >> 2) << 6);
    red[r * 16 + tx] = apv[a];
  }
  __syncthreads();
  if (tid < 128) {
    float m = red[tid * 16];
#pragma unroll
    for (int t = 1; t < 16; ++t) m = fmaxf(m, red[tid * 16 + t]);
    atomicMax(&ap[ib0 + tid], __float_as_uint(m));
  }
  __syncthreads();
#pragma unroll
  for (int a = 0; a < 8; ++a) {
    int r = ty * 4 + (a & 3) + ((a >> 2) << 6);
    red[r * 16 + tx] = anv[a];
  }
  __syncthreads();
  if (tid < 128) {
    float m = red[tid * 16];
#pragma unroll
    for (int t = 1; t < 16; ++t) m = fminf(m, red[tid * 16 + t]);
    atomicMin(&an[ib0 + tid], __float_as_uint(m));
  }
}

__global__ void tl_pass2_fb(const float* __restrict__ ap, const float* __restrict__ an,
                            float* __restrict__ out) {
  int r = blockIdx.x * 256 + threadIdx.x;
  float v = fmaxf(0.0f, MARGIN + ap[r] - an[r]) * (1.0f / (float)N);
#pragma unroll
  for (int off = 32; off > 0; off >>= 1) v += __shfl_down(v, off, 64);
  __shared__ float red[4];
  int lane = threadIdx.x & 63, w = threadIdx.x >> 6;
  if (lane == 0) red[w] = v;
  __syncthreads();
  if (threadIdx.x == 0) atomicAdd(out, red[0] + red[1] + red[2] + red[3]);
}

// ---------------- launch ----------------

extern "C" void kernel_launch(void* const* d_in, const int* in_sizes, int n_in,
                              void* d_out, int out_size, void* d_ws, size_t ws_size,
                              hipStream_t stream) {
  const float* feat = (const float*)d_in[0];
  const int* labels = (const int*)d_in[1];
  float* out = (float*)d_out;

  // ws: norms[N] f32 | ap[N] u32 | an[N] u32 | perm[N] i32 | labp[N] i32 |
  //     off[520] i32 | P[N*D] bf16   (P offset 16B-aligned)
  float* norms = (float*)d_ws;
  unsigned* ap = (unsigned*)(norms + N);
  unsigned* an = ap + N;
  int* perm = (int*)(an + N);
  int* labp = perm + N;
  int* offg = labp + N;
  unsigned short* P = (unsigned short*)(offg + 520);
  const size_t NEED = (size_t)5 * N * 4 + 520 * 4 + (size_t)N * D * 2;

  if (ws_size >= NEED) {
    tl_sortk<<<1, 1024, 0, stream>>>(labels, perm, labp, offg);
    tl_pass0p<<<N / 4, 256, 0, stream>>>(feat, perm, norms, ap, an, P, out);
    dim3 grid1(16, N / 128);  // 16 j-splits x 64 strips = 1024 blocks (3/CU)
    tl_pass1s<<<grid1, 256, 0, stream>>>(P, labp, norms, offg, ap, an);
    tl_pass2f<<<N / 256, 256, 0, stream>>>(ap, an, norms, out);
  } else {
    float* apf = (float*)ap;
    float* anf = (float*)an;
    tl_pass0_fb<<<N / 4, 256, 0, stream>>>(feat, norms, apf, anf, out);
    dim3 grid1(FB_JSPLIT, N / 128);
    tl_pass1_fb<<<grid1, 256, 0, stream>>>(feat, labels, norms, (unsigned*)apf, (unsigned*)anf);
    tl_pass2_fb<<<N / 256, 256, 0, stream>>>(apf, anf, out);
  }
}

// Round 4
// 135.391 us; speedup vs baseline: 1.2366x; 1.0963x over previous
//
#include <hip/hip_runtime.h>

// TripletLoss on MI355X — round 11: back to the round-8 no-spill regime,
// occupancy via LDS only.
//
//  - Rounds 9/10 postmortem: __launch_bounds__ min-waves (4 then 3) forced
//    VGPR caps below the body's ~190-reg live set -> scratch spill
//    (WRITE_SIZE 183MB/50MB). Round 8 proved the same core compiles
//    spill-free at (256,2): VGPR 124, WRITE 2MB, 44.4us.
//  - This round: (256,2) + full unroll (round-8 codegen regime) + BK=64
//    double buffer = 32KB LDS (round 8's 64KB was the 2-blocks/CU limiter).
//    VGPR ~124-170 + 32KB -> 3 blocks/CU, 1.5x resident waves, cross-block
//    overlap absorbs the per-barrier vmcnt drain.
//  - Blocks do 2 j-tiles (8 chunks) each; grid 32x64=2048 tiles evenly for
//    3/CU or 4/CU residency.

constexpr int N = 8192;
constexpr int D = 256;
constexpr float MARGIN = 0.3f;
constexpr float NEG_FALLBACK = 1e6f;
constexpr float TBIG = 1e30f;

typedef __attribute__((ext_vector_type(8))) __bf16 bf16x8;
typedef __attribute__((ext_vector_type(4))) float f32x4;

__device__ __forceinline__ unsigned enc_f(float f) {
  unsigned u = __float_as_uint(f);
  return (u >> 31) ? ~u : (u | 0x80000000u);
}
__device__ __forceinline__ float dec_f(unsigned e) {
  unsigned u = (e >> 31) ? (e ^ 0x80000000u) : ~e;
  return __uint_as_float(u);
}
__device__ __forceinline__ unsigned short f2bf_rtn(float x) {
  unsigned u = __float_as_uint(x);
  return (unsigned short)((u + 0x7fffu + ((u >> 16) & 1u)) >> 16);
}

// ---------------- sort: counting sort by label, 1 block x 1024 threads ------

__global__ __launch_bounds__(1024)
void tl_sortk(const int* __restrict__ labels, int* __restrict__ perm,
              int* __restrict__ labp, int* __restrict__ offg) {
  __shared__ int hist[512];
  __shared__ int wsum[8];
  __shared__ int wbase[8];
  const int tid = threadIdx.x;
  const int lane = tid & 63;
  const int w = tid >> 6;
  if (tid < 512) hist[tid] = 0;
  __syncthreads();
  int l8[8];
#pragma unroll
  for (int k = 0; k < 8; ++k) {
    l8[k] = labels[tid + k * 1024];  // coalesced
    atomicAdd(&hist[l8[k]], 1);      // LDS atomic
  }
  __syncthreads();
  int v = 0, sc = 0;
  if (tid < 512) {  // waves 0..7 scan the 512-entry histogram
    v = hist[tid];
    sc = v;
#pragma unroll
    for (int d = 1; d < 64; d <<= 1) {
      int t = __shfl_up(sc, d, 64);
      if (lane >= d) sc += t;
    }
    if (lane == 63) wsum[w] = sc;
  }
  __syncthreads();
  if (tid == 0) {
    int a = 0;
#pragma unroll
    for (int i = 0; i < 8; ++i) { wbase[i] = a; a += wsum[i]; }
  }
  __syncthreads();
  if (tid < 512) {
    const int excl = wbase[w] + sc - v;
    offg[tid] = excl;
    hist[tid] = excl;  // reuse as running scatter counters
  }
  if (tid == 0) offg[512] = N;
  __syncthreads();
#pragma unroll
  for (int k = 0; k < 8; ++k) {
    const int pos = atomicAdd(&hist[l8[k]], 1);  // LDS atomic
    perm[pos] = tid + k * 1024;
    labp[pos] = l8[k];
  }
}

// ---------------- pass 0: permuted bf16 convert + norms + init ----------------

__global__ void tl_pass0p(const float* __restrict__ feat, const int* __restrict__ perm,
                          float* __restrict__ norms, unsigned* __restrict__ ap,
                          unsigned* __restrict__ an, unsigned short* __restrict__ P,
                          float* __restrict__ out) {
  const int p = blockIdx.x * 4 + (threadIdx.x >> 6);
  const int lane = threadIdx.x & 63;
  const int src = perm[p];
  float4 f = reinterpret_cast<const float4*>(feat + (size_t)src * D)[lane];
  ushort4 h;
  h.x = f2bf_rtn(f.x); h.y = f2bf_rtn(f.y); h.z = f2bf_rtn(f.z); h.w = f2bf_rtn(f.w);
  reinterpret_cast<ushort4*>(P + (size_t)p * D)[lane] = h;
  float s = fmaf(f.x, f.x, fmaf(f.y, f.y, fmaf(f.z, f.z, f.w * f.w)));
#pragma unroll
  for (int off = 32; off > 0; off >>= 1) s += __shfl_down(s, off, 64);
  if (lane == 0) {
    norms[p] = s;
    ap[p] = enc_f(-TBIG);
    an[p] = enc_f(TBIG);
  }
  if (p == 0 && lane == 0) out[0] = 0.0f;
}

// ---------------- pass 1: persistent strip Gram + sorted mining ----------------

__global__ __launch_bounds__(256, 2)
void tl_pass1s(const unsigned short* __restrict__ P, const int* __restrict__ labp,
               const float* __restrict__ norms, const int* __restrict__ offg,
               unsigned* __restrict__ ap, unsigned* __restrict__ an) {
  __shared__ unsigned short lB[2][128][64];  // 32 KB double-buffered B chunk

  const int tid = threadIdx.x;
  const int wave = tid >> 6;
  const int lane = tid & 63;
  const int c = lane & 15;
  const int q = lane >> 4;
  const int i0 = blockIdx.y * 128;   // strip base row (permuted space)
  const int j0 = blockIdx.x * 256;   // this block's column range: 2 j-tiles
  const int wrow = i0 + wave * 32;   // wave's 32 output rows

  // careful j-range for this strip: columns whose label matches any strip row
  const int lo = offg[labp[i0]];
  const int hi = offg[labp[i0 + 127] + 1];

  // A fragments in registers for the whole block: af[a][kg] = P[row][kg*32+q*8]
  bf16x8 af[2][8];
#pragma unroll
  for (int a = 0; a < 2; ++a)
#pragma unroll
    for (int t2 = 0; t2 < 8; ++t2)
      af[a][t2] = *(const bf16x8*)(P + (size_t)(wrow + a * 16 + c) * D + t2 * 32 + q * 8);

  f32x4 acc[2][8];
#pragma unroll
  for (int a = 0; a < 2; ++a)
#pragma unroll
    for (int b = 0; b < 8; ++b) acc[a][b] = (f32x4){0.f, 0.f, 0.f, 0.f};

  float vp[2][4], vn[2][4];
#pragma unroll
  for (int a = 0; a < 2; ++a)
#pragma unroll
    for (int r = 0; r < 4; ++r) { vp[a][r] = -TBIG; vn[a][r] = TBIG; }

  const int rsub = lane >> 3;  // 0..7: row within 8-row DMA group
  const int g7 = lane & 7;     // 8-short (16B) column group within 64-short row

  // Stage one [128 cols][64 K] chunk. LDS dest linear (wave-uniform base +
  // lane*16B); SOURCE pre-swizzled so LDS[r][g] = P[r][kc + (g ^ (r&7))*8].
  // All macro args are compile-time literals (full unroll below).
#define STAGE(BUF, JT, KC)                                                              \
  do {                                                                                  \
    const int jb_ = j0 + (JT) * 128;                                                    \
    _Pragma("unroll") for (int t = 0; t < 4; ++t) {                                     \
      const int rA_ = wave * 32 + t * 8;                                                \
      const int sg_ = g7 ^ rsub;                                                        \
      const unsigned short* gp_ = P + (size_t)(jb_ + rA_ + rsub) * D + (KC) + sg_ * 8;  \
      __builtin_amdgcn_global_load_lds(                                                 \
          (const __attribute__((address_space(1))) void*)gp_,                           \
          (__attribute__((address_space(3))) void*)&lB[BUF][rA_][0], 16, 0, 0);         \
    }                                                                                   \
  } while (0)

  STAGE(0, 0, 0);
  __syncthreads();

  // 8 chunks: s = jt*4 + kk, buffer parity s&1, FULL unroll (round-8 regime)
#pragma unroll
  for (int s = 0; s < 8; ++s) {
    const int jt = s >> 2;
    const int kk = s & 3;
    if (s < 7) STAGE((s + 1) & 1, (s + 1) >> 2, ((s + 1) & 3) * 64);

    // compute chunk s from buffer s&1: K-groups kk*2, kk*2+1
#pragma unroll
    for (int ks = 0; ks < 2; ++ks) {
      const int gsel = ((ks * 4 + q) ^ (c & 7)) * 8;
      bf16x8 bfr[8];
#pragma unroll
      for (int b = 0; b < 8; ++b)
        bfr[b] = *(const bf16x8*)&lB[s & 1][b * 16 + c][gsel];
#pragma unroll
      for (int a = 0; a < 2; ++a)
#pragma unroll
        for (int b = 0; b < 8; ++b)
          acc[a][b] = __builtin_amdgcn_mfma_f32_16x16x32_bf16(
              af[a][kk * 2 + ks], bfr[b], acc[a][b], 0, 0, 0);
    }

    if (kk == 3) {  // j-tile complete -> mine it
      const int jb0 = j0 + jt * 128;
      const bool careful = (jb0 < hi) && (jb0 + 128 > lo);  // block-uniform
      if (!careful) {
        // pure negatives: 2 VALU ops per element
#pragma unroll
        for (int b = 0; b < 8; ++b) {
          const float njb = norms[jb0 + b * 16 + c];
#pragma unroll
          for (int a = 0; a < 2; ++a)
#pragma unroll
            for (int r = 0; r < 4; ++r)
              vn[a][r] = fminf(vn[a][r], fmaf(-2.f, acc[a][b][r], njb));
        }
      } else {
        int lj[8], cj[8];
        float nj[8];
#pragma unroll
        for (int b = 0; b < 8; ++b) {
          cj[b] = jb0 + b * 16 + c;
          nj[b] = norms[cj[b]];
          lj[b] = labp[cj[b]];
        }
#pragma unroll
        for (int a = 0; a < 2; ++a)
#pragma unroll
          for (int r = 0; r < 4; ++r) {
            const int rg = wrow + a * 16 + q * 4 + r;  // C/D row = quad*4 + reg
            const int li = labp[rg];
            float vpl = vp[a][r], vnl = vn[a][r];
#pragma unroll
            for (int b = 0; b < 8; ++b) {
              const float t = fmaf(-2.f, acc[a][b][r], nj[b]);
              const bool sm = (lj[b] == li);
              const bool dg = (cj[b] == rg);
              vpl = fmaxf(vpl, (sm && !dg) ? t : -TBIG);
              vnl = fminf(vnl, sm ? TBIG : t);
            }
            vp[a][r] = vpl;
            vn[a][r] = vnl;
          }
      }
#pragma unroll
      for (int a = 0; a < 2; ++a)
#pragma unroll
        for (int b = 0; b < 8; ++b) acc[a][b] = (f32x4){0.f, 0.f, 0.f, 0.f};
    }
    __syncthreads();
  }
#undef STAGE

  // epilogue once per block: reduce over the 16 c-lanes, then 1 atomic pair/row
#pragma unroll
  for (int a = 0; a < 2; ++a)
#pragma unroll
    for (int r = 0; r < 4; ++r) {
      float p = vp[a][r], n = vn[a][r];
#pragma unroll
      for (int m = 1; m < 16; m <<= 1) {
        p = fmaxf(p, __shfl_xor(p, m, 64));
        n = fminf(n, __shfl_xor(n, m, 64));
      }
      if (c == 0) {
        const int rg = wrow + a * 16 + q * 4 + r;
        atomicMax(&ap[rg], enc_f(p));
        atomicMin(&an[rg], enc_f(n));
      }
    }
}

// ---------------- pass 2: per-row loss -> mean (permuted space; mean invariant) --

__global__ void tl_pass2f(const unsigned* __restrict__ ap, const unsigned* __restrict__ an,
                          const float* __restrict__ norms, float* __restrict__ out) {
  int r = blockIdx.x * 256 + threadIdx.x;
  float ni = norms[r];
  float tpv = dec_f(ap[r]);
  float tnv = dec_f(an[r]);
  float dap = (tpv < -1e29f) ? 0.f : sqrtf(fmaxf(ni + tpv, 0.f));
  float dan = (tnv > 1e29f) ? NEG_FALLBACK : sqrtf(fmaxf(ni + tnv, 0.f));
  float v = fmaxf(0.f, MARGIN + dap - dan) * (1.0f / (float)N);
#pragma unroll
  for (int off = 32; off > 0; off >>= 1) v += __shfl_down(v, off, 64);
  __shared__ float red[4];
  int lane = threadIdx.x & 63, w = threadIdx.x >> 6;
  if (lane == 0) red[w] = v;
  __syncthreads();
  if (threadIdx.x == 0) atomicAdd(out, red[0] + red[1] + red[2] + red[3]);
}

// ---------------- fallback fp32 path (small ws) — round-1 known-good ----------------

constexpr int FB_BK = 32;
constexpr int FB_JSPLIT = 8;
constexpr int FB_JRANGE = N / FB_JSPLIT;
constexpr int FB_LDS = 132;

__global__ void tl_pass0_fb(const float* __restrict__ feat, float* __restrict__ norms,
                            float* __restrict__ ap, float* __restrict__ an,
                            float* __restrict__ out) {
  int row = blockIdx.x * 4 + (threadIdx.x >> 6);
  int lane = threadIdx.x & 63;
  float4 f = reinterpret_cast<const float4*>(feat + (size_t)row * D)[lane];
  float s = f.x * f.x + f.y * f.y + f.z * f.z + f.w * f.w;
#pragma unroll
  for (int off = 32; off > 0; off >>= 1) s += __shfl_down(s, off, 64);
  if (lane == 0) { norms[row] = s; ap[row] = 0.0f; an[row] = NEG_FALLBACK; }
  if (row == 0 && lane == 0) out[0] = 0.0f;
}

__global__ __launch_bounds__(256, 2)
void tl_pass1_fb(const float* __restrict__ feat, const int* __restrict__ labels,
                 const float* __restrict__ norms,
                 unsigned int* __restrict__ ap, unsigned int* __restrict__ an) {
  __shared__ float As[FB_BK][FB_LDS];
  __shared__ float Bs[FB_BK][FB_LDS];
  const int tid = threadIdx.x;
  const int tx = tid & 15, ty = tid >> 4;
  const int ib0 = blockIdx.y * 128;
  const int jbase = blockIdx.x * FB_JRANGE;
  float ni[8]; int li[8]; int ri[8];
#pragma unroll
  for (int a = 0; a < 8; ++a) {
    int r = ty * 4 + (a & 3) + ((a >> 2) << 6);
    ri[a] = ib0 + r; ni[a] = norms[ri[a]]; li[a] = labels[ri[a]];
  }
  float apv[8], anv[8];
#pragma unroll
  for (int a = 0; a < 8; ++a) { apv[a] = 0.0f; anv[a] = NEG_FALLBACK; }
  for (int jt = 0; jt < FB_JRANGE; jt += 128) {
    const int jb = jbase + jt;
    float acc[8][8];
#pragma unroll
    for (int a = 0; a < 8; ++a)
#pragma unroll
      for (int b = 0; b < 8; ++b) acc[a][b] = 0.0f;
    for (int kc = 0; kc < D; kc += FB_BK) {
#pragma unroll
      for (int u = 0; u < 4; ++u) {
        int lin = tid + u * 256;
        int row = lin >> 3, c4 = lin & 7;
        float4 va = *reinterpret_cast<const float4*>(feat + (size_t)(ib0 + row) * D + kc + c4 * 4);
        As[c4 * 4 + 0][row] = va.x; As[c4 * 4 + 1][row] = va.y;
        As[c4 * 4 + 2][row] = va.z; As[c4 * 4 + 3][row] = va.w;
        float4 vb = *reinterpret_cast<const float4*>(feat + (size_t)(jb + row) * D + kc + c4 * 4);
        Bs[c4 * 4 + 0][row] = vb.x; Bs[c4 * 4 + 1][row] = vb.y;
        Bs[c4 * 4 + 2][row] = vb.z; Bs[c4 * 4 + 3][row] = vb.w;
      }
      __syncthreads();
#pragma unroll 8
      for (int k = 0; k < FB_BK; ++k) {
        float4 a0 = *reinterpret_cast<const float4*>(&As[k][ty * 4]);
        float4 a1 = *reinterpret_cast<const float4*>(&As[k][64 + ty * 4]);
        float4 b0 = *reinterpret_cast<const float4*>(&Bs[k][tx * 4]);
        float4 b1 = *reinterpret_cast<const float4*>(&Bs[k][64 + tx * 4]);
        float av[8] = {a0.x, a0.y, a0.z, a0.w, a1.x, a1.y, a1.z, a1.w};
        float bv[8] = {b0.x, b0.y, b0.z, b0.w, b1.x, b1.y, b1.z, b1.w};
#pragma unroll
        for (int a = 0; a < 8; ++a)
#pragma unroll
          for (int b = 0; b < 8; ++b) acc[a][b] = fmaf(av[a], bv[b], acc[a][b]);
      }
      __syncthreads();
    }
#pragma unroll
    for (int b = 0; b < 8; ++b) {
      int cjx = jb + tx * 4 + (b & 3) + ((b >> 2) << 6);
      float njx = norms[cjx]; int ljx = labels[cjx];
#pragma unroll
      for (int a = 0; a < 8; ++a) {
        float sq = fmaxf(ni[a] + njx - 2.0f * acc[a][b], 0.0f);
        float dist = sqrtf(sq);
        if (li[a] == ljx) { if (ri[a] != cjx) apv[a] = fmaxf(apv[a], dist); }
        else anv[a] = fminf(anv[a], dist);
      }
    }
  }
  __syncthreads();
  float* red = &As[0][0];
#pragma unroll
  for (int a = 0; a < 8; ++a) {
    int r = ty * 4 + (a & 3) + ((a >> 2) << 6);
    red[r * 16 + tx] = apv[a];
  }
  __syncthreads();
  if (tid < 128) {
    float m = red[tid * 16];
#pragma unroll
    for (int t = 1; t < 16; ++t) m = fmaxf(m, red[tid * 16 + t]);
    atomicMax(&ap[ib0 + tid], __float_as_uint(m));
  }
  __syncthreads();
#pragma unroll
  for (int a = 0; a < 8; ++a) {
    int r = ty * 4 + (a & 3) + ((a >> 2) << 6);
    red[r * 16 + tx] = anv[a];
  }
  __syncthreads();
  if (tid < 128) {
    float m = red[tid * 16];
#pragma unroll
    for (int t = 1; t < 16; ++t) m = fminf(m, red[tid * 16 + t]);
    atomicMin(&an[ib0 + tid], __float_as_uint(m));
  }
}

__global__ void tl_pass2_fb(const float* __restrict__ ap, const float* __restrict__ an,
                            float* __restrict__ out) {
  int r = blockIdx.x * 256 + threadIdx.x;
  float v = fmaxf(0.0f, MARGIN + ap[r] - an[r]) * (1.0f / (float)N);
#pragma unroll
  for (int off = 32; off > 0; off >>= 1) v += __shfl_down(v, off, 64);
  __shared__ float red[4];
  int lane = threadIdx.x & 63, w = threadIdx.x >> 6;
  if (lane == 0) red[w] = v;
  __syncthreads();
  if (threadIdx.x == 0) atomicAdd(out, red[0] + red[1] + red[2] + red[3]);
}

// ---------------- launch ----------------

extern "C" void kernel_launch(void* const* d_in, const int* in_sizes, int n_in,
                              void* d_out, int out_size, void* d_ws, size_t ws_size,
                              hipStream_t stream) {
  const float* feat = (const float*)d_in[0];
  const int* labels = (const int*)d_in[1];
  float* out = (float*)d_out;

  // ws: norms[N] f32 | ap[N] u32 | an[N] u32 | perm[N] i32 | labp[N] i32 |
  //     off[520] i32 | P[N*D] bf16   (P offset 16B-aligned)
  float* norms = (float*)d_ws;
  unsigned* ap = (unsigned*)(norms + N);
  unsigned* an = ap + N;
  int* perm = (int*)(an + N);
  int* labp = perm + N;
  int* offg = labp + N;
  unsigned short* P = (unsigned short*)(offg + 520);
  const size_t NEED = (size_t)5 * N * 4 + 520 * 4 + (size_t)N * D * 2;

  if (ws_size >= NEED) {
    tl_sortk<<<1, 1024, 0, stream>>>(labels, perm, labp, offg);
    tl_pass0p<<<N / 4, 256, 0, stream>>>(feat, perm, norms, ap, an, P, out);
    dim3 grid1(32, N / 128);  // 32 j-splits (2 tiles each) x 64 strips = 2048 blocks
    tl_pass1s<<<grid1, 256, 0, stream>>>(P, labp, norms, offg, ap, an);
    tl_pass2f<<<N / 256, 256, 0, stream>>>(ap, an, norms, out);
  } else {
    float* apf = (float*)ap;
    float* anf = (float*)an;
    tl_pass0_fb<<<N / 4, 256, 0, stream>>>(feat, norms, apf, anf, out);
    dim3 grid1(FB_JSPLIT, N / 128);
    tl_pass1_fb<<<grid1, 256, 0, stream>>>(feat, labels, norms, (unsigned*)apf, (unsigned*)anf);
    tl_pass2_fb<<<N / 256, 256, 0, stream>>>(apf, anf, out);
  }
}

// Round 5
// 112.615 us; speedup vs baseline: 1.4867x; 1.2023x over previous
//
#include <hip/hip_runtime.h>

// TripletLoss on MI355X — round 12: counted-vmcnt ring-of-3 pipeline (T3+T4).
//
//  - Round-11 postmortem: spill fixed (VGPR 100, WRITE 8MB) but BK=64 halved
//    MFMA-per-barrier while keeping a full vmcnt(0) drain per barrier ->
//    MfmaUtil fell to 20% (R1's 64-MFMA intervals gave 29%). The drain is
//    structural with 2 buffers: prefetch issued in step s must land by the
//    end-of-s barrier.
//  - Fix: 3-buffer ring (48KB), prefetch depth 2. Step s issues STAGE(s+2);
//    end-of-step wait is `s_waitcnt vmcnt(4)` + raw s_barrier -> STAGE(s+2)'s
//    4 loads stay in flight across the barrier (m201 recipe). Only the sync
//    line changes vs the verified R11 macros.
//  - Hazards: buf (s+2)%3 last read at step s-1; those ds_reads are
//    lgkmcnt-waited before their MFMAs, which precede the end-of-(s-1)
//    barrier, which precedes STAGE issue at s. vmcnt(4) at end of s
//    guarantees STAGE(s+1) landed before step s+1 reads it.
//  - 48KB -> 3 blocks/CU at VGPR<=170; 4 j-tiles/block; grid 16x64=1024.

constexpr int N = 8192;
constexpr int D = 256;
constexpr float MARGIN = 0.3f;
constexpr float NEG_FALLBACK = 1e6f;
constexpr float TBIG = 1e30f;

typedef __attribute__((ext_vector_type(8))) __bf16 bf16x8;
typedef __attribute__((ext_vector_type(4))) float f32x4;

__device__ __forceinline__ unsigned enc_f(float f) {
  unsigned u = __float_as_uint(f);
  return (u >> 31) ? ~u : (u | 0x80000000u);
}
__device__ __forceinline__ float dec_f(unsigned e) {
  unsigned u = (e >> 31) ? (e ^ 0x80000000u) : ~e;
  return __uint_as_float(u);
}
__device__ __forceinline__ unsigned short f2bf_rtn(float x) {
  unsigned u = __float_as_uint(x);
  return (unsigned short)((u + 0x7fffu + ((u >> 16) & 1u)) >> 16);
}

// ---------------- sort: counting sort by label, 1 block x 1024 threads ------

__global__ __launch_bounds__(1024)
void tl_sortk(const int* __restrict__ labels, int* __restrict__ perm,
              int* __restrict__ labp, int* __restrict__ offg) {
  __shared__ int hist[512];
  __shared__ int wsum[8];
  __shared__ int wbase[8];
  const int tid = threadIdx.x;
  const int lane = tid & 63;
  const int w = tid >> 6;
  if (tid < 512) hist[tid] = 0;
  __syncthreads();
  int l8[8];
#pragma unroll
  for (int k = 0; k < 8; ++k) {
    l8[k] = labels[tid + k * 1024];  // coalesced
    atomicAdd(&hist[l8[k]], 1);      // LDS atomic
  }
  __syncthreads();
  int v = 0, sc = 0;
  if (tid < 512) {  // waves 0..7 scan the 512-entry histogram
    v = hist[tid];
    sc = v;
#pragma unroll
    for (int d = 1; d < 64; d <<= 1) {
      int t = __shfl_up(sc, d, 64);
      if (lane >= d) sc += t;
    }
    if (lane == 63) wsum[w] = sc;
  }
  __syncthreads();
  if (tid == 0) {
    int a = 0;
#pragma unroll
    for (int i = 0; i < 8; ++i) { wbase[i] = a; a += wsum[i]; }
  }
  __syncthreads();
  if (tid < 512) {
    const int excl = wbase[w] + sc - v;
    offg[tid] = excl;
    hist[tid] = excl;  // reuse as running scatter counters
  }
  if (tid == 0) offg[512] = N;
  __syncthreads();
#pragma unroll
  for (int k = 0; k < 8; ++k) {
    const int pos = atomicAdd(&hist[l8[k]], 1);  // LDS atomic
    perm[pos] = tid + k * 1024;
    labp[pos] = l8[k];
  }
}

// ---------------- pass 0: permuted bf16 convert + norms + init ----------------

__global__ void tl_pass0p(const float* __restrict__ feat, const int* __restrict__ perm,
                          float* __restrict__ norms, unsigned* __restrict__ ap,
                          unsigned* __restrict__ an, unsigned short* __restrict__ P,
                          float* __restrict__ out) {
  const int p = blockIdx.x * 4 + (threadIdx.x >> 6);
  const int lane = threadIdx.x & 63;
  const int src = perm[p];
  float4 f = reinterpret_cast<const float4*>(feat + (size_t)src * D)[lane];
  ushort4 h;
  h.x = f2bf_rtn(f.x); h.y = f2bf_rtn(f.y); h.z = f2bf_rtn(f.z); h.w = f2bf_rtn(f.w);
  reinterpret_cast<ushort4*>(P + (size_t)p * D)[lane] = h;
  float s = fmaf(f.x, f.x, fmaf(f.y, f.y, fmaf(f.z, f.z, f.w * f.w)));
#pragma unroll
  for (int off = 32; off > 0; off >>= 1) s += __shfl_down(s, off, 64);
  if (lane == 0) {
    norms[p] = s;
    ap[p] = enc_f(-TBIG);
    an[p] = enc_f(TBIG);
  }
  if (p == 0 && lane == 0) out[0] = 0.0f;
}

// ---------------- pass 1: persistent strip Gram + sorted mining ----------------

__global__ __launch_bounds__(256, 2)
void tl_pass1s(const unsigned short* __restrict__ P, const int* __restrict__ labp,
               const float* __restrict__ norms, const int* __restrict__ offg,
               unsigned* __restrict__ ap, unsigned* __restrict__ an) {
  __shared__ unsigned short lB[3][128][64];  // 48 KB ring-of-3 B chunks

  const int tid = threadIdx.x;
  const int wave = tid >> 6;
  const int lane = tid & 63;
  const int c = lane & 15;
  const int q = lane >> 4;
  const int i0 = blockIdx.y * 128;   // strip base row (permuted space)
  const int j0 = blockIdx.x * 512;   // this block's column range: 4 j-tiles
  const int wrow = i0 + wave * 32;   // wave's 32 output rows

  // careful j-range for this strip: columns whose label matches any strip row
  const int lo = offg[labp[i0]];
  const int hi = offg[labp[i0 + 127] + 1];

  // A fragments in registers for the whole block: af[a][kg] = P[row][kg*32+q*8]
  bf16x8 af[2][8];
#pragma unroll
  for (int a = 0; a < 2; ++a)
#pragma unroll
    for (int t2 = 0; t2 < 8; ++t2)
      af[a][t2] = *(const bf16x8*)(P + (size_t)(wrow + a * 16 + c) * D + t2 * 32 + q * 8);

  f32x4 acc[2][8];
#pragma unroll
  for (int a = 0; a < 2; ++a)
#pragma unroll
    for (int b = 0; b < 8; ++b) acc[a][b] = (f32x4){0.f, 0.f, 0.f, 0.f};

  float vp[2][4], vn[2][4];
#pragma unroll
  for (int a = 0; a < 2; ++a)
#pragma unroll
    for (int r = 0; r < 4; ++r) { vp[a][r] = -TBIG; vn[a][r] = TBIG; }

  const int rsub = lane >> 3;  // 0..7: row within 8-row DMA group
  const int g7 = lane & 7;     // 8-short (16B) column group within 64-short row

  // Stage one [128 cols][64 K] chunk into ring buffer BUF. LDS dest linear
  // (wave-uniform base + lane*16B); SOURCE pre-swizzled so
  // LDS[r][g] = P[r][kc + (g ^ (r&7))*8].
#define STAGE(BUF, S1)                                                                  \
  do {                                                                                  \
    const int jb_ = j0 + ((S1) >> 2) * 128;                                             \
    const int kc_ = ((S1) & 3) * 64;                                                    \
    _Pragma("unroll") for (int t = 0; t < 4; ++t) {                                     \
      const int rA_ = wave * 32 + t * 8;                                                \
      const int sg_ = g7 ^ rsub;                                                        \
      const unsigned short* gp_ = P + (size_t)(jb_ + rA_ + rsub) * D + kc_ + sg_ * 8;   \
      __builtin_amdgcn_global_load_lds(                                                 \
          (const __attribute__((address_space(1))) void*)gp_,                           \
          (__attribute__((address_space(3))) void*)&lB[BUF][rA_][0], 16, 0, 0);         \
    }                                                                                   \
  } while (0)

  // Counted-vmcnt barrier: STAGE(s+2)'s 4 loads stay in flight (T4).
#define WAITB4 do { asm volatile("s_waitcnt vmcnt(4)" ::: "memory"); \
                    __builtin_amdgcn_s_barrier(); } while (0)
#define WAITB0 do { asm volatile("s_waitcnt vmcnt(0)" ::: "memory"); \
                    __builtin_amdgcn_s_barrier(); } while (0)

  STAGE(0, 0);
  STAGE(1, 1);
  WAITB4;  // chunk 0 landed; chunk 1 in flight

  // 16 steps: s = jt*4 + kk; ring index s%3; prefetch depth 2; FULL unroll.
#pragma unroll
  for (int s = 0; s < 16; ++s) {
    const int jt = s >> 2;
    const int kk = s & 3;
    if (s + 2 < 16) STAGE((s + 2) % 3, s + 2);

    // compute chunk s from ring buffer s%3: K-groups kk*2, kk*2+1
#pragma unroll
    for (int ks = 0; ks < 2; ++ks) {
      const int gsel = ((ks * 4 + q) ^ (c & 7)) * 8;
      bf16x8 bfr[8];
#pragma unroll
      for (int b = 0; b < 8; ++b)
        bfr[b] = *(const bf16x8*)&lB[s % 3][b * 16 + c][gsel];
#pragma unroll
      for (int a = 0; a < 2; ++a)
#pragma unroll
        for (int b = 0; b < 8; ++b)
          acc[a][b] = __builtin_amdgcn_mfma_f32_16x16x32_bf16(
              af[a][kk * 2 + ks], bfr[b], acc[a][b], 0, 0, 0);
    }

    if (kk == 3) {  // j-tile complete -> mine it
      const int jb0 = j0 + jt * 128;
      const bool careful = (jb0 < hi) && (jb0 + 128 > lo);  // block-uniform
      if (!careful) {
        // pure negatives: 2 VALU ops per element
#pragma unroll
        for (int b = 0; b < 8; ++b) {
          const float njb = norms[jb0 + b * 16 + c];
#pragma unroll
          for (int a = 0; a < 2; ++a)
#pragma unroll
            for (int r = 0; r < 4; ++r)
              vn[a][r] = fminf(vn[a][r], fmaf(-2.f, acc[a][b][r], njb));
        }
      } else {
        int lj[8], cj[8];
        float nj[8];
#pragma unroll
        for (int b = 0; b < 8; ++b) {
          cj[b] = jb0 + b * 16 + c;
          nj[b] = norms[cj[b]];
          lj[b] = labp[cj[b]];
        }
#pragma unroll
        for (int a = 0; a < 2; ++a)
#pragma unroll
          for (int r = 0; r < 4; ++r) {
            const int rg = wrow + a * 16 + q * 4 + r;  // C/D row = quad*4 + reg
            const int li = labp[rg];
            float vpl = vp[a][r], vnl = vn[a][r];
#pragma unroll
            for (int b = 0; b < 8; ++b) {
              const float t = fmaf(-2.f, acc[a][b][r], nj[b]);
              const bool sm = (lj[b] == li);
              const bool dg = (cj[b] == rg);
              vpl = fmaxf(vpl, (sm && !dg) ? t : -TBIG);
              vnl = fminf(vnl, sm ? TBIG : t);
            }
            vp[a][r] = vpl;
            vn[a][r] = vnl;
          }
      }
#pragma unroll
      for (int a = 0; a < 2; ++a)
#pragma unroll
        for (int b = 0; b < 8; ++b) acc[a][b] = (f32x4){0.f, 0.f, 0.f, 0.f};
    }

    // end-of-step sync: STAGE(s+1) must have landed; STAGE(s+2) stays in flight
    if (s < 14) {
      WAITB4;
    } else if (s == 14) {
      WAITB0;  // only STAGE(15) outstanding
    }  // s == 15: no barrier; epilogue is shfl+atomics only
  }
#undef STAGE
#undef WAITB4
#undef WAITB0

  // epilogue once per block: reduce over the 16 c-lanes, then 1 atomic pair/row
#pragma unroll
  for (int a = 0; a < 2; ++a)
#pragma unroll
    for (int r = 0; r < 4; ++r) {
      float p = vp[a][r], n = vn[a][r];
#pragma unroll
      for (int m = 1; m < 16; m <<= 1) {
        p = fmaxf(p, __shfl_xor(p, m, 64));
        n = fminf(n, __shfl_xor(n, m, 64));
      }
      if (c == 0) {
        const int rg = wrow + a * 16 + q * 4 + r;
        atomicMax(&ap[rg], enc_f(p));
        atomicMin(&an[rg], enc_f(n));
      }
    }
}

// ---------------- pass 2: per-row loss -> mean (permuted space; mean invariant) --

__global__ void tl_pass2f(const unsigned* __restrict__ ap, const unsigned* __restrict__ an,
                          const float* __restrict__ norms, float* __restrict__ out) {
  int r = blockIdx.x * 256 + threadIdx.x;
  float ni = norms[r];
  float tpv = dec_f(ap[r]);
  float tnv = dec_f(an[r]);
  float dap = (tpv < -1e29f) ? 0.f : sqrtf(fmaxf(ni + tpv, 0.f));
  float dan = (tnv > 1e29f) ? NEG_FALLBACK : sqrtf(fmaxf(ni + tnv, 0.f));
  float v = fmaxf(0.f, MARGIN + dap - dan) * (1.0f / (float)N);
#pragma unroll
  for (int off = 32; off > 0; off >>= 1) v += __shfl_down(v, off, 64);
  __shared__ float red[4];
  int lane = threadIdx.x & 63, w = threadIdx.x >> 6;
  if (lane == 0) red[w] = v;
  __syncthreads();
  if (threadIdx.x == 0) atomicAdd(out, red[0] + red[1] + red[2] + red[3]);
}

// ---------------- fallback fp32 path (small ws) — round-1 known-good ----------------

constexpr int FB_BK = 32;
constexpr int FB_JSPLIT = 8;
constexpr int FB_JRANGE = N / FB_JSPLIT;
constexpr int FB_LDS = 132;

__global__ void tl_pass0_fb(const float* __restrict__ feat, float* __restrict__ norms,
                            float* __restrict__ ap, float* __restrict__ an,
                            float* __restrict__ out) {
  int row = blockIdx.x * 4 + (threadIdx.x >> 6);
  int lane = threadIdx.x & 63;
  float4 f = reinterpret_cast<const float4*>(feat + (size_t)row * D)[lane];
  float s = f.x * f.x + f.y * f.y + f.z * f.z + f.w * f.w;
#pragma unroll
  for (int off = 32; off > 0; off >>= 1) s += __shfl_down(s, off, 64);
  if (lane == 0) { norms[row] = s; ap[row] = 0.0f; an[row] = NEG_FALLBACK; }
  if (row == 0 && lane == 0) out[0] = 0.0f;
}

__global__ __launch_bounds__(256, 2)
void tl_pass1_fb(const float* __restrict__ feat, const int* __restrict__ labels,
                 const float* __restrict__ norms,
                 unsigned int* __restrict__ ap, unsigned int* __restrict__ an) {
  __shared__ float As[FB_BK][FB_LDS];
  __shared__ float Bs[FB_BK][FB_LDS];
  const int tid = threadIdx.x;
  const int tx = tid & 15, ty = tid >> 4;
  const int ib0 = blockIdx.y * 128;
  const int jbase = blockIdx.x * FB_JRANGE;
  float ni[8]; int li[8]; int ri[8];
#pragma unroll
  for (int a = 0; a < 8; ++a) {
    int r = ty * 4 + (a & 3) + ((a >> 2) << 6);
    ri[a] = ib0 + r; ni[a] = norms[ri[a]]; li[a] = labels[ri[a]];
  }
  float apv[8], anv[8];
#pragma unroll
  for (int a = 0; a < 8; ++a) { apv[a] = 0.0f; anv[a] = NEG_FALLBACK; }
  for (int jt = 0; jt < FB_JRANGE; jt += 128) {
    const int jb = jbase + jt;
    float acc[8][8];
#pragma unroll
    for (int a = 0; a < 8; ++a)
#pragma unroll
      for (int b = 0; b < 8; ++b) acc[a][b] = 0.0f;
    for (int kc = 0; kc < D; kc += FB_BK) {
#pragma unroll
      for (int u = 0; u < 4; ++u) {
        int lin = tid + u * 256;
        int row = lin >> 3, c4 = lin & 7;
        float4 va = *reinterpret_cast<const float4*>(feat + (size_t)(ib0 + row) * D + kc + c4 * 4);
        As[c4 * 4 + 0][row] = va.x; As[c4 * 4 + 1][row] = va.y;
        As[c4 * 4 + 2][row] = va.z; As[c4 * 4 + 3][row] = va.w;
        float4 vb = *reinterpret_cast<const float4*>(feat + (size_t)(jb + row) * D + kc + c4 * 4);
        Bs[c4 * 4 + 0][row] = vb.x; Bs[c4 * 4 + 1][row] = vb.y;
        Bs[c4 * 4 + 2][row] = vb.z; Bs[c4 * 4 + 3][row] = vb.w;
      }
      __syncthreads();
#pragma unroll 8
      for (int k = 0; k < FB_BK; ++k) {
        float4 a0 = *reinterpret_cast<const float4*>(&As[k][ty * 4]);
        float4 a1 = *reinterpret_cast<const float4*>(&As[k][64 + ty * 4]);
        float4 b0 = *reinterpret_cast<const float4*>(&Bs[k][tx * 4]);
        float4 b1 = *reinterpret_cast<const float4*>(&Bs[k][64 + tx * 4]);
        float av[8] = {a0.x, a0.y, a0.z, a0.w, a1.x, a1.y, a1.z, a1.w};
        float bv[8] = {b0.x, b0.y, b0.z, b0.w, b1.x, b1.y, b1.z, b1.w};
#pragma unroll
        for (int a = 0; a < 8; ++a)
#pragma unroll
          for (int b = 0; b < 8; ++b) acc[a][b] = fmaf(av[a], bv[b], acc[a][b]);
      }
      __syncthreads();
    }
#pragma unroll
    for (int b = 0; b < 8; ++b) {
      int cjx = jb + tx * 4 + (b & 3) + ((b >> 2) << 6);
      float njx = norms[cjx]; int ljx = labels[cjx];
#pragma unroll
      for (int a = 0; a < 8; ++a) {
        float sq = fmaxf(ni[a] + njx - 2.0f * acc[a][b], 0.0f);
        float dist = sqrtf(sq);
        if (li[a] == ljx) { if (ri[a] != cjx) apv[a] = fmaxf(apv[a], dist); }
        else anv[a] = fminf(anv[a], dist);
      }
    }
  }
  __syncthreads();
  float* red = &As[0][0];
#pragma unroll
  for (int a = 0; a < 8; ++a) {
    int r = ty * 4 + (a & 3) + ((a >> 2) << 6);
    red[r * 16 + tx] = apv[a];
  }
  __syncthreads();
  if (tid < 128) {
    float m = red[tid * 16];
#pragma unroll
    for (int t = 1; t < 16; ++t) m = fmaxf(m, red[tid * 16 + t]);
    atomicMax(&ap[ib0 + tid], __float_as_uint(m));
  }
  __syncthreads();
#pragma unroll
  for (int a = 0; a < 8; ++a) {
    int r = ty * 4 + (a & 3) + ((a >> 2) << 6);
    red[r * 16 + tx] = anv[a];
  }
  __syncthreads();
  if (tid < 128) {
    float m = red[tid * 16];
#pragma unroll
    for (int t = 1; t < 16; ++t) m = fminf(m, red[tid * 16 + t]);
    atomicMin(&an[ib0 + tid], __float_as_uint(m));
  }
}

__global__ void tl_pass2_fb(const float* __restrict__ ap, const float* __restrict__ an,
                            float* __restrict__ out) {
  int r = blockIdx.x * 256 + threadIdx.x;
  float v = fmaxf(0.0f, MARGIN + ap[r] - an[r]) * (1.0f / (float)N);
#pragma unroll
  for (int off = 32; off > 0; off >>= 1) v += __shfl_down(v, off, 64);
  __shared__ float red[4];
  int lane = threadIdx.x & 63, w = threadIdx.x >> 6;
  if (lane == 0) red[w] = v;
  __syncthreads();
  if (threadIdx.x == 0) atomicAdd(out, red[0] + red[1] + red[2] + red[3]);
}

// ---------------- launch ----------------

extern "C" void kernel_launch(void* const* d_in, const int* in_sizes, int n_in,
                              void* d_out, int out_size, void* d_ws, size_t ws_size,
                              hipStream_t stream) {
  const float* feat = (const float*)d_in[0];
  const int* labels = (const int*)d_in[1];
  float* out = (float*)d_out;

  // ws: norms[N] f32 | ap[N] u32 | an[N] u32 | perm[N] i32 | labp[N] i32 |
  //     off[520] i32 | P[N*D] bf16   (P offset 16B-aligned)
  float* norms = (float*)d_ws;
  unsigned* ap = (unsigned*)(norms + N);
  unsigned* an = ap + N;
  int* perm = (int*)(an + N);
  int* labp = perm + N;
  int* offg = labp + N;
  unsigned short* P = (unsigned short*)(offg + 520);
  const size_t NEED = (size_t)5 * N * 4 + 520 * 4 + (size_t)N * D * 2;

  if (ws_size >= NEED) {
    tl_sortk<<<1, 1024, 0, stream>>>(labels, perm, labp, offg);
    tl_pass0p<<<N / 4, 256, 0, stream>>>(feat, perm, norms, ap, an, P, out);
    dim3 grid1(16, N / 128);  // 16 j-splits (4 tiles each) x 64 strips = 1024 blocks
    tl_pass1s<<<grid1, 256, 0, stream>>>(P, labp, norms, offg, ap, an);
    tl_pass2f<<<N / 256, 256, 0, stream>>>(ap, an, norms, out);
  } else {
    float* apf = (float*)ap;
    float* anf = (float*)an;
    tl_pass0_fb<<<N / 4, 256, 0, stream>>>(feat, norms, apf, anf, out);
    dim3 grid1(FB_JSPLIT, N / 128);
    tl_pass1_fb<<<grid1, 256, 0, stream>>>(feat, labels, norms, (unsigned*)apf, (unsigned*)anf);
    tl_pass2_fb<<<N / 256, 256, 0, stream>>>(apf, anf, out);
  }
}